// Round 6
// baseline (609.788 us; speedup 1.0000x reference)
//
#include <hip/hip_runtime.h>

typedef __bf16 bf16x8 __attribute__((ext_vector_type(8)));
typedef float f32x4 __attribute__((ext_vector_type(4)));

#define MFMA(a, b, c) __builtin_amdgcn_mfma_f32_16x16x32_bf16((a), (b), (c), 0, 0, 0)

// ---------------------------------------------------------------------------
// prep: transpose the 4 weight matrices to bf16 [n][k] (MFMA B-operand layout)
// and convert E to bf16.
// ---------------------------------------------------------------------------
__global__ __launch_bounds__(256)
void prep_kernel(const float* __restrict__ Wq, const float* __restrict__ Wk,
                 const float* __restrict__ Wv, const float* __restrict__ Wo,
                 const float* __restrict__ E,
                 __bf16* __restrict__ WT, __bf16* __restrict__ Ebf)
{
    __shared__ float tl[32][33];
    const int bx = blockIdx.x, t = threadIdx.x;
    if (bx < 1024) {
        const int wi = bx >> 8, tile = bx & 255;
        const float* W = wi == 0 ? Wq : wi == 1 ? Wk : wi == 2 ? Wv : Wo;
        __bf16* dst = WT + (size_t)wi * 512 * 512;
        const int k0 = (tile >> 4) << 5, n0 = (tile & 15) << 5;
        const int tx = t & 31, ty = t >> 5;
        #pragma unroll
        for (int i = 0; i < 4; ++i) {
            int r = ty + i * 8;
            tl[r][tx] = W[(size_t)(k0 + r) * 512 + n0 + tx];
        }
        __syncthreads();
        #pragma unroll
        for (int i = 0; i < 4; ++i) {
            int r = ty + i * 8;
            dst[(size_t)(n0 + r) * 512 + k0 + tx] = (__bf16)tl[tx][r];
        }
    } else {
        int idx = (bx - 1024) * 256 + t;
        for (int i = idx; i < 2048 * 64; i += 8 * 256)
            Ebf[i] = (__bf16)E[i];
    }
}

// ---------------------------------------------------------------------------
// proj: X(4096x512 fp32) @ W + b -> Q,K head-split bf16 [b*8+h][s][64];
// V is emitted TRANSPOSED: [b*8+h][dh][s] (B-operand layout for PV MFMA).
// 128x64 tiles, register prefetch.
// ---------------------------------------------------------------------------
__global__ __launch_bounds__(256, 3)
void proj_kernel(const float* __restrict__ xq, const float* __restrict__ xk,
                 const float* __restrict__ xv, const __bf16* __restrict__ WT,
                 const float* __restrict__ bq, const float* __restrict__ bk,
                 const float* __restrict__ bv,
                 __bf16* __restrict__ outQ, __bf16* __restrict__ outK,
                 __bf16* __restrict__ outVT)
{
    __shared__ __bf16 As[128][72];
    __shared__ __bf16 Bs[64][72];
    const int t = threadIdx.x;
    const int z = blockIdx.y;
    const float* x = z == 0 ? xq : z == 1 ? xk : xv;
    const float* bias = z == 0 ? bq : z == 1 ? bk : bv;
    const __bf16* Wt = WT + (size_t)z * (512 * 512);

    const int bx = blockIdx.x;
    const int m0 = (bx >> 3) << 7;
    const int n0 = (bx & 7) << 6;
    const int w = t >> 6, lane = t & 63, quad = lane >> 4, l16 = lane & 15;

    const int ar = t >> 1, ac = (t & 1) << 5;
    const int br = t >> 2, bc = (t & 3) << 4;

    float4 xr[8];
    int4 wr0, wr1;
    {
        const float4* xs = (const float4*)(x + (size_t)(m0 + ar) * 512 + ac);
        #pragma unroll
        for (int j = 0; j < 8; ++j) xr[j] = xs[j];
        const int4* wsrc = (const int4*)(Wt + (size_t)(n0 + br) * 512 + bc);
        wr0 = wsrc[0]; wr1 = wsrc[1];
    }

    f32x4 acc[2][4];
    #pragma unroll
    for (int rb = 0; rb < 2; ++rb)
        #pragma unroll
        for (int nt = 0; nt < 4; ++nt) acc[rb][nt] = (f32x4)0.f;

    for (int k0 = 0; k0 < 512; k0 += 64) {
        __syncthreads();
        {
            __bf16 tb[32];
            #pragma unroll
            for (int j = 0; j < 8; ++j) {
                tb[j * 4 + 0] = (__bf16)xr[j].x;
                tb[j * 4 + 1] = (__bf16)xr[j].y;
                tb[j * 4 + 2] = (__bf16)xr[j].z;
                tb[j * 4 + 3] = (__bf16)xr[j].w;
            }
            *(int4*)&As[ar][ac]      = ((int4*)tb)[0];
            *(int4*)&As[ar][ac + 8]  = ((int4*)tb)[1];
            *(int4*)&As[ar][ac + 16] = ((int4*)tb)[2];
            *(int4*)&As[ar][ac + 24] = ((int4*)tb)[3];
            *(int4*)&Bs[br][bc]     = wr0;
            *(int4*)&Bs[br][bc + 8] = wr1;
        }
        __syncthreads();
        if (k0 + 64 < 512) {
            const float4* xs = (const float4*)(x + (size_t)(m0 + ar) * 512 + k0 + 64 + ac);
            #pragma unroll
            for (int j = 0; j < 8; ++j) xr[j] = xs[j];
            const int4* wsrc = (const int4*)(Wt + (size_t)(n0 + br) * 512 + k0 + 64 + bc);
            wr0 = wsrc[0]; wr1 = wsrc[1];
        }
        bf16x8 bf[8];
        #pragma unroll
        for (int nt = 0; nt < 4; ++nt) {
            bf[nt * 2]     = *(const bf16x8*)&Bs[nt * 16 + l16][quad * 8];
            bf[nt * 2 + 1] = *(const bf16x8*)&Bs[nt * 16 + l16][32 + quad * 8];
        }
        #pragma unroll
        for (int rb = 0; rb < 2; ++rb) {
            bf16x8 a0 = *(const bf16x8*)&As[w * 32 + rb * 16 + l16][quad * 8];
            bf16x8 a1 = *(const bf16x8*)&As[w * 32 + rb * 16 + l16][32 + quad * 8];
            #pragma unroll
            for (int nt = 0; nt < 4; ++nt) {
                acc[rb][nt] = MFMA(a0, bf[nt * 2], acc[rb][nt]);
                acc[rb][nt] = MFMA(a1, bf[nt * 2 + 1], acc[rb][nt]);
            }
        }
    }
    #pragma unroll
    for (int rb = 0; rb < 2; ++rb) {
        #pragma unroll
        for (int nt = 0; nt < 4; ++nt) {
            const int n = n0 + nt * 16 + l16;
            const float bb = bias[n];
            const int h = n >> 6, dh = n & 63;
            #pragma unroll
            for (int i = 0; i < 4; ++i) {
                const int m = m0 + w * 32 + rb * 16 + quad * 4 + i;
                const int b = m >> 11, s = m & 2047;
                const __bf16 val = (__bf16)(acc[rb][nt][i] + bb);
                if (z == 2) {
                    outVT[((size_t)((b * 8 + h) * 64 + dh)) * 2048 + s] = val;
                } else {
                    __bf16* outp = z == 0 ? outQ : outK;
                    outp[(((size_t)(b * 8 + h) * 2048 + s) << 6) + dh] = val;
                }
            }
        }
    }
}

// ---------------------------------------------------------------------------
// attn v5: ZERO LDS staging, ONE barrier per block. All MFMA operands are
// contiguous 16 B in global (L2/L3-hot): Q/K/E in pass A, P/V^T in pass B.
// Pass A: QK + skewed QE -> exp -> scattered bf16 P stores (no drain),
//   row-sums. One syncthreads+fence.
// Pass B: P A-frags + V^T B-frags from global, PV MFMA, nontemporal
//   normalized fp32 attn stores. Then ctx + upper-triangle zero.
// ---------------------------------------------------------------------------
__global__ __launch_bounds__(256, 4)
void attn_kernel(const __bf16* __restrict__ Qh, const __bf16* __restrict__ Kh,
                 const __bf16* __restrict__ VhT, const __bf16* __restrict__ Eb,
                 __bf16* __restrict__ Pout, float* __restrict__ attn,
                 __bf16* __restrict__ ctx)
{
    __shared__ float linv_s[64];

    const int t = threadIdx.x;
    const int bx = blockIdx.x;
    const int tt = bx & 31;
    const int bh = ((bx & 255) >> 5) + ((bx >> 8) << 3);
    const int q0 = (bx < 256 ? (31 - tt) : tt) << 6;   // complementary pairing
    const int w = t >> 6, lane = t & 63, quad = lane >> 4, l16 = lane & 15;
    const int qw = w << 4;

    const __bf16* Qg = Qh + (size_t)bh * (2048 * 64);
    const __bf16* Kg = Kh + (size_t)bh * (2048 * 64);
    const __bf16* Vt = VhT + (size_t)bh * (64 * 2048);
    __bf16* Pg = Pout + (size_t)bh * (2048 * 2048);
    float* attng = attn + (size_t)bh * (2048 * 2048);

    const int nkt = (q0 >> 6) + 1;
    const float csc = 0.125f * 1.44269504f;

    const int qrow = q0 + qw + l16;                    // this lane's A-frag row
    const bf16x8 qa0 = *(const bf16x8*)(Qg + (size_t)qrow * 64 + quad * 8);
    const bf16x8 qa1 = *(const bf16x8*)(Qg + (size_t)qrow * 64 + 32 + quad * 8);

    float lsum[4] = {0.f, 0.f, 0.f, 0.f};

    // ---------------- pass A: logits -> P (no barriers) ----------------
    for (int kt = 0; kt < nkt; ++kt) {
        const int k0 = kt << 6;
        f32x4 aqk[4];
        #pragma unroll
        for (int nt = 0; nt < 4; ++nt) {
            const __bf16* kp = Kg + (size_t)(k0 + nt * 16 + l16) * 64 + quad * 8;
            bf16x8 b0 = *(const bf16x8*)kp;
            bf16x8 b1 = *(const bf16x8*)(kp + 32);
            aqk[nt] = MFMA(qa0, b0, (f32x4)0.f);
            aqk[nt] = MFMA(qa1, b1, aqk[nt]);
        }
        f32x4 aqe[5];
        #pragma unroll
        for (int jj = 0; jj < 5; ++jj) {
            int e = 1984 - q0 + k0 + 48 - qw + jj * 16 + l16;
            if (e > 2047) e = 2047;                    // over-band rows are masked
            const __bf16* ep = Eb + (size_t)e * 64 + quad * 8;
            bf16x8 b0 = *(const bf16x8*)ep;
            bf16x8 b1 = *(const bf16x8*)(ep + 32);
            aqe[jj] = MFMA(qa0, b0, (f32x4)0.f);
            aqe[jj] = MFMA(qa1, b1, aqe[jj]);
        }
        #pragma unroll
        for (int i = 0; i < 4; ++i) {
            const int d  = quad * 4 + i;
            const int qq = q0 + qw + d;
            const int sp = (l16 + 15 - d) & 15;
            const bool hi = l16 > d;
            __bf16* prow = Pg + (size_t)qq * 2048 + k0 + l16;
            #pragma unroll
            for (int nt = 0; nt < 4; ++nt) {
                float g0 = __shfl(aqe[nt][i], sp, 16);
                float g1 = __shfl(aqe[nt + 1][i], sp, 16);
                float qe = hi ? g1 : g0;
                float ev = (k0 + nt * 16 + l16 <= qq)
                         ? exp2f((aqk[nt][i] + qe) * csc) : 0.f;
                lsum[i] += ev;
                prow[nt * 16] = (__bf16)ev;
            }
        }
    }
    #pragma unroll
    for (int i = 0; i < 4; ++i) {
        float v = lsum[i];
        #pragma unroll
        for (int m = 1; m < 16; m <<= 1) v += __shfl_xor(v, m, 16);
        if (l16 == 0) linv_s[qw + quad * 4 + i] = 1.0f / v;
    }
    __syncthreads();      // single drain point: P stores + linv visible
    __threadfence();      // L1 invalidate so pass B sees pass A's P

    const float li = linv_s[qw + l16];       // normalizer for A-frag rows
    float linvr[4];
    #pragma unroll
    for (int i = 0; i < 4; ++i) linvr[i] = linv_s[qw + quad * 4 + i];

    f32x4 acc_o[4];
    #pragma unroll
    for (int i = 0; i < 4; ++i) acc_o[i] = (f32x4)0.f;

    // ---------------- pass B: PV + normalized attn (no barriers) -----------
    for (int kt = 0; kt < nkt; ++kt) {
        const int k0 = kt << 6;
        const __bf16* prow = Pg + (size_t)qrow * 2048 + k0 + quad * 8;
        int4 praw0 = *(const int4*)prow;
        int4 praw1 = *(const int4*)(prow + 32);
        bf16x8 pa0 = *(bf16x8*)&praw0;
        bf16x8 pa1 = *(bf16x8*)&praw1;

        #pragma unroll
        for (int dt = 0; dt < 4; ++dt) {
            const __bf16* vp = Vt + (size_t)(dt * 16 + l16) * 2048 + k0 + quad * 8;
            bf16x8 vb0 = *(const bf16x8*)vp;
            bf16x8 vb1 = *(const bf16x8*)(vp + 32);
            acc_o[dt] = MFMA(pa0, vb0, acc_o[dt]);
            acc_o[dt] = MFMA(pa1, vb1, acc_o[dt]);
        }

        float* arow = attng + (size_t)qrow * 2048 + k0 + quad * 8;
        f32x4 o;
        o[0] = (float)pa0[0] * li; o[1] = (float)pa0[1] * li;
        o[2] = (float)pa0[2] * li; o[3] = (float)pa0[3] * li;
        __builtin_nontemporal_store(o, (f32x4*)arow);
        o[0] = (float)pa0[4] * li; o[1] = (float)pa0[5] * li;
        o[2] = (float)pa0[6] * li; o[3] = (float)pa0[7] * li;
        __builtin_nontemporal_store(o, (f32x4*)(arow + 4));
        o[0] = (float)pa1[0] * li; o[1] = (float)pa1[1] * li;
        o[2] = (float)pa1[2] * li; o[3] = (float)pa1[3] * li;
        __builtin_nontemporal_store(o, (f32x4*)(arow + 32));
        o[0] = (float)pa1[4] * li; o[1] = (float)pa1[5] * li;
        o[2] = (float)pa1[6] * li; o[3] = (float)pa1[7] * li;
        __builtin_nontemporal_store(o, (f32x4*)(arow + 36));
    }

    {   // context out (scaled), merged-head layout [b][q][h*64+d]
        const int b = bh >> 3, h = bh & 7;
        #pragma unroll
        for (int dt = 0; dt < 4; ++dt) {
            #pragma unroll
            for (int i = 0; i < 4; ++i) {
                const int qq = q0 + qw + quad * 4 + i;
                const int d = dt * 16 + l16;
                ctx[((size_t)(b * 2048 + qq) * 512) + h * 64 + d] =
                    (__bf16)(acc_o[dt][i] * linvr[i]);
            }
        }
    }
    {   // zero the masked attn region: cols [q0+64, 2048)
        const int kend = q0 + 64;
        const int zc = 2048 - kend;
        if (zc > 0) {
            const int zq = zc >> 2;
            const f32x4 z4 = (f32x4)0.f;
            for (int idx = t; idx < 64 * zq; idx += 256) {
                int r = idx / zq, c = idx - r * zq;
                __builtin_nontemporal_store(
                    z4, (f32x4*)&attng[(size_t)(q0 + r) * 2048 + kend + c * 4]);
            }
        }
    }
}

// ---------------------------------------------------------------------------
// outproj: ctx(bf16 4096x512) @ Wo + bo -> fp32 d_out, register prefetch.
// ---------------------------------------------------------------------------
__global__ __launch_bounds__(256, 2)
void outproj_kernel(const __bf16* __restrict__ ctx, const __bf16* __restrict__ WoT,
                    const float* __restrict__ bo, float* __restrict__ out)
{
    __shared__ __bf16 As[64][72];
    __shared__ __bf16 Bs[64][72];
    const int t = threadIdx.x;
    const int bx = blockIdx.x;
    const int m0 = (bx >> 3) << 6;
    const int n0 = (bx & 7) << 6;
    const int w = t >> 6, lane = t & 63, quad = lane >> 4, l16 = lane & 15;
    const int r = t >> 2, c0 = (t & 3) << 4;

    int4 ar0, ar1, br0, br1;
    {
        const int4* asrc = (const int4*)(ctx + (size_t)(m0 + r) * 512 + c0);
        ar0 = asrc[0]; ar1 = asrc[1];
        const int4* bsrc = (const int4*)(WoT + (size_t)(n0 + r) * 512 + c0);
        br0 = bsrc[0]; br1 = bsrc[1];
    }

    f32x4 acc[4];
    #pragma unroll
    for (int i = 0; i < 4; ++i) acc[i] = (f32x4)0.f;

    for (int k0 = 0; k0 < 512; k0 += 64) {
        __syncthreads();
        *(int4*)&As[r][c0]     = ar0;
        *(int4*)&As[r][c0 + 8] = ar1;
        *(int4*)&Bs[r][c0]     = br0;
        *(int4*)&Bs[r][c0 + 8] = br1;
        __syncthreads();
        if (k0 + 64 < 512) {
            const int4* asrc = (const int4*)(ctx + (size_t)(m0 + r) * 512 + k0 + 64 + c0);
            ar0 = asrc[0]; ar1 = asrc[1];
            const int4* bsrc = (const int4*)(WoT + (size_t)(n0 + r) * 512 + k0 + 64 + c0);
            br0 = bsrc[0]; br1 = bsrc[1];
        }
        bf16x8 a0 = *(const bf16x8*)&As[(w << 4) + l16][quad * 8];
        bf16x8 a1 = *(const bf16x8*)&As[(w << 4) + l16][32 + quad * 8];
        #pragma unroll
        for (int nt = 0; nt < 4; ++nt) {
            bf16x8 b0 = *(const bf16x8*)&Bs[nt * 16 + l16][quad * 8];
            bf16x8 b1 = *(const bf16x8*)&Bs[nt * 16 + l16][32 + quad * 8];
            acc[nt] = MFMA(a0, b0, acc[nt]);
            acc[nt] = MFMA(a1, b1, acc[nt]);
        }
    }
    #pragma unroll
    for (int nt = 0; nt < 4; ++nt) {
        const int n = n0 + nt * 16 + l16;
        const float bb = bo[n];
        #pragma unroll
        for (int i = 0; i < 4; ++i) {
            const int m = m0 + (w << 4) + quad * 4 + i;
            out[(size_t)m * 512 + n] = acc[nt][i] + bb;
        }
    }
}

// ---------------------------------------------------------------------------
extern "C" void kernel_launch(void* const* d_in, const int* in_sizes, int n_in,
                              void* d_out, int out_size, void* d_ws, size_t ws_size,
                              hipStream_t stream) {
    const float* v  = (const float*)d_in[0];
    const float* k  = (const float*)d_in[1];
    const float* q  = (const float*)d_in[2];
    /* mask d_in[3] unused (causality is structural) */
    const float* Wq = (const float*)d_in[4];
    const float* bq = (const float*)d_in[5];
    const float* Wk = (const float*)d_in[6];
    const float* bk = (const float*)d_in[7];
    const float* Wv = (const float*)d_in[8];
    const float* bv = (const float*)d_in[9];
    const float* Wo = (const float*)d_in[10];
    const float* bo = (const float*)d_in[11];
    const float* E  = (const float*)d_in[12];

    float* out  = (float*)d_out;
    float* attn = out + (size_t)2 * 2048 * 512;   // outputs concatenated: out, attn

    char* ws = (char*)d_ws;
    __bf16* WT   = (__bf16*)ws;                                  // 2 MB
    __bf16* Ebf  = (__bf16*)(ws + (size_t)(4 * 512 * 512) * 2);  // 256 KB
    __bf16* Qh   = Ebf + (size_t)2048 * 64;
    __bf16* Kh   = Qh + (size_t)16 * 2048 * 64;
    __bf16* VhT  = Kh + (size_t)16 * 2048 * 64;                  // [bh][dh][s]
    __bf16* ctx  = VhT + (size_t)16 * 2048 * 64;
    __bf16* Pout = ctx + (size_t)16 * 2048 * 64;                 // 134 MB

    prep_kernel<<<1032, 256, 0, stream>>>(Wq, Wk, Wv, Wo, E, WT, Ebf);
    proj_kernel<<<dim3(256, 3), 256, 0, stream>>>(q, k, v, WT, bq, bk, bv, Qh, Kh, VhT);
    attn_kernel<<<512, 256, 0, stream>>>(Qh, Kh, VhT, Ebf, Pout, attn, ctx);
    outproj_kernel<<<512, 256, 0, stream>>>(ctx, WT + (size_t)3 * 512 * 512, bo, out);
}